// Round 6
// baseline (786.668 us; speedup 1.0000x reference)
//
#include <hip/hip_runtime.h>

#define IN_SIZE 256
#define N_NODES 1024
#define DEG 32
#define BATCH 16384
#define OUT_SIZE 16
#define COLS 8                        // batch columns per single-wave block
#define N_ROWS (IN_SIZE + N_NODES)    // 1280 activation rows (fp32 in LDS)
#define NGRP (N_NODES / 8)            // 128 groups of 8 nodes

// RNE float -> bf16
__device__ __forceinline__ unsigned short f2bf_rne(float f) {
    const unsigned u = __float_as_uint(f);
    return (unsigned short)((u + 0x7FFFu + ((u >> 16) & 1u)) >> 16);
}

// overflow-free tanh: s = e^{-2|z|}, t = sign(z)*(1-s)/(1+s)
__device__ __forceinline__ float tanh6(float z) {
    const float s = __expf(-2.0f * fabsf(z));
    const float r = __builtin_amdgcn_rcpf(1.0f + s);
    return copysignf(fmaf(-s, r, r), z);
}

// ---------------------------------------------------------------------------
// Runtime dtype detector (unchanged).
// ---------------------------------------------------------------------------
__global__ __launch_bounds__(64) void ne_detect(const void* __restrict__ xraw,
                                                int* __restrict__ flag) {
    const unsigned short* xb = (const unsigned short*)xraw;
    const int tid = threadIdx.x;
    int plausible = 0;
    for (int k = tid; k < 2048; k += 64) {
        const float v = __uint_as_float((unsigned)xb[2 * k] << 16);
        const float a = fabsf(v);
        plausible += (a == 0.0f) || (a > 1e-3f && a < 1e3f) ? 1 : 0;
    }
    for (int off = 32; off > 0; off >>= 1) plausible += __shfl_down(plausible, off);
    if (tid == 0) *flag = (plausible >= (2048 * 9) / 10) ? 1 : 0;
}

// ---------------------------------------------------------------------------
// Weights -> fp32 plus the TRANSPOSED within-group hazard table:
//   hst[n][s] = sum_r w[n][r] * [ idx[n][r] == 256 + (n & ~7) + s ]   (s < n&7)
// At group G, after t_{G*8+s} is broadcast, every lane j folds
// z_j += hst[G*8+j][s] * t_s — all register indices compile-time.
// ---------------------------------------------------------------------------
__global__ __launch_bounds__(256) void ne_prep(const void* __restrict__ wraw,
                                               const int* __restrict__ idxs,
                                               float* __restrict__ wf,
                                               float* __restrict__ hst,
                                               const int* __restrict__ flag) {
    const int isbf16 = *flag;                    // uniform
    const int tid = blockIdx.x * 256 + threadIdx.x;
    const int stride = gridDim.x * 256;
    const unsigned short* wb = (const unsigned short*)wraw;
    const float* wsrc = (const float*)wraw;
    for (int k = tid; k < N_NODES * DEG; k += stride)
        wf[k] = isbf16 ? __uint_as_float((unsigned)wb[k] << 16) : wsrc[k];
    for (int n = tid; n < N_NODES; n += stride) {
        const int j = n & 7;
        const int base = n & ~7;
        for (int s = 0; s < 8; ++s) {
            float h = 0.0f;
            if (s < j) {
                const int target = IN_SIZE + base + s;
                for (int r = 0; r < DEG; ++r) {
                    if (idxs[n * DEG + r] == target) {
                        h += isbf16 ? __uint_as_float((unsigned)wb[n * DEG + r] << 16)
                                    : wsrc[n * DEG + r];
                    }
                }
            }
            hst[n * 8 + s] = h;
        }
    }
}

// ---------------------------------------------------------------------------
// Lane-owns-node restructure. lane = c*8 + j: j = node-in-group, c = column.
// Per group G (8 nodes): each lane computes the FULL 32-elem dot of its node
// for its column (no reduce, no masked ops), then an 8-step serial phase:
// tanh -> 3-VALU broadcast (quad_perm + row_half_mirror + cndmask) -> fold.
// Gathers for G+1 issue after write(G) (single-wave in-order DS), so stale
// rows are exactly group G+1's own -> hazard window <= 7, covered by hst.
// ids/w stream straight from in_idxs/wf (no repack), 1-2 groups ahead.
// ---------------------------------------------------------------------------
__global__ __launch_bounds__(64) void ne_forward(const void* __restrict__ xraw,
                                                 const float* __restrict__ wf,
                                                 const int* __restrict__ in_idxs,
                                                 const float* __restrict__ hst,
                                                 void* __restrict__ outraw,
                                                 const int* __restrict__ flag) {
    __shared__ float act[N_ROWS * COLS];         // 40960 B -> 4 blocks/CU
    const int lane = threadIdx.x;
    const int myj = lane & 7;                    // node-in-group 0..7
    const int c = lane >> 3;                     // batch column 0..7
    const int c0 = blockIdx.x * COLS;
    const int isbf16 = *flag;                    // uniform
    float* outf = (float*)outraw;
    unsigned short* outb = (unsigned short*)outraw;

    // ---- zero node rows so stale gathers read exactly 0.0 ----
    {
        float4* az = (float4*)(act + IN_SIZE * COLS);   // 2048 float4
#pragma unroll
        for (int t = 0; t < 32; ++t) az[t * 64 + lane] = make_float4(0.f, 0.f, 0.f, 0.f);
    }
    // ---- seed input rows 0..255 from raw x ----
    {
        const int b = lane >> 3;                 // column to seed
        const int seg = lane & 7;                // 32-element segment
        if (isbf16) {
            const unsigned short* xb =
                (const unsigned short*)xraw + (size_t)(c0 + b) * IN_SIZE + seg * 32;
#pragma unroll
            for (int t = 0; t < 4; ++t) {
                const uint4 v = *(const uint4*)(xb + t * 8);
                const int k0 = seg * 32 + t * 8;
                act[(k0 + 0) * COLS + b] = __uint_as_float(v.x << 16);
                act[(k0 + 1) * COLS + b] = __uint_as_float(v.x & 0xFFFF0000u);
                act[(k0 + 2) * COLS + b] = __uint_as_float(v.y << 16);
                act[(k0 + 3) * COLS + b] = __uint_as_float(v.y & 0xFFFF0000u);
                act[(k0 + 4) * COLS + b] = __uint_as_float(v.z << 16);
                act[(k0 + 5) * COLS + b] = __uint_as_float(v.z & 0xFFFF0000u);
                act[(k0 + 6) * COLS + b] = __uint_as_float(v.w << 16);
                act[(k0 + 7) * COLS + b] = __uint_as_float(v.w & 0xFFFF0000u);
            }
        } else {
            const float* xs = (const float*)xraw + (size_t)(c0 + b) * IN_SIZE + seg * 32;
#pragma unroll
            for (int t = 0; t < 8; ++t) {
                const float4 v = *(const float4*)(xs + t * 4);
                const int k0 = seg * 32 + t * 4;
                act[(k0 + 0) * COLS + b] = v.x;
                act[(k0 + 1) * COLS + b] = v.y;
                act[(k0 + 2) * COLS + b] = v.z;
                act[(k0 + 3) * COLS + b] = v.w;
            }
        }
    }
    // single wave: in-order DS pipeline -> gathers below see the seed; no barrier

    // per-lane streams: node (G*8+myj)'s 32 ids / 32 weights / 8 hst floats
    const int4*   pI  = (const int4*)in_idxs + myj * 8;     // [G*64 + r]
    const float4* pW  = (const float4*)wf + myj * 8;        // [G*64 + r]
    const float4* pH4 = (const float4*)hst + myj * 2;       // [G*16 + k]

    int4 idv[8]; float4 wv[8]; float4 hv[2];
    float g[32];

    // ---- prologue: ids(0); gathers(0); loads w(0), hs(0), ids(1) ----
#pragma unroll
    for (int r = 0; r < 8; ++r) idv[r] = pI[r];
#pragma unroll
    for (int r4 = 0; r4 < 8; ++r4) {
        g[4 * r4 + 0] = act[idv[r4].x * COLS + c];
        g[4 * r4 + 1] = act[idv[r4].y * COLS + c];
        g[4 * r4 + 2] = act[idv[r4].z * COLS + c];
        g[4 * r4 + 3] = act[idv[r4].w * COLS + c];
    }
#pragma unroll
    for (int r = 0; r < 8; ++r) wv[r] = pW[r];
    hv[0] = pH4[0]; hv[1] = pH4[1];
#pragma unroll
    for (int r = 0; r < 8; ++r) idv[r] = pI[64 + r];

    float z;

// serial step s: tanh (valid in lane-set s), 3-VALU broadcast to the 8-lane
// group, fold with hst coeff (zero for myj <= s -> unconditional fma safe).
#define S_STEP(s, HS)                                                                  \
    {                                                                                  \
        const float tt = tanh6(z);                                                     \
        const int qp = __builtin_amdgcn_mov_dpp(__float_as_int(tt),                    \
                                                ((s) & 3) * 0x55, 0xF, 0xF, true);     \
        const int mir = __builtin_amdgcn_mov_dpp(qp, 0x141, 0xF, 0xF, true);           \
        const float bc = __int_as_float((((myj ^ (s)) & 4) ? mir : qp));               \
        z = fmaf((HS), bc, z);                                                         \
    }

#define DOT8                                                                           \
    float p0 = g[0] * wv[0].x, p1 = g[4] * wv[1].x, p2 = g[8] * wv[2].x,               \
          p3 = g[12] * wv[3].x, p4 = g[16] * wv[4].x, p5 = g[20] * wv[5].x,            \
          p6 = g[24] * wv[6].x, p7 = g[28] * wv[7].x;                                  \
    p0 = fmaf(g[1], wv[0].y, p0);  p0 = fmaf(g[2], wv[0].z, p0);  p0 = fmaf(g[3], wv[0].w, p0);  \
    p1 = fmaf(g[5], wv[1].y, p1);  p1 = fmaf(g[6], wv[1].z, p1);  p1 = fmaf(g[7], wv[1].w, p1);  \
    p2 = fmaf(g[9], wv[2].y, p2);  p2 = fmaf(g[10], wv[2].z, p2); p2 = fmaf(g[11], wv[2].w, p2); \
    p3 = fmaf(g[13], wv[3].y, p3); p3 = fmaf(g[14], wv[3].z, p3); p3 = fmaf(g[15], wv[3].w, p3); \
    p4 = fmaf(g[17], wv[4].y, p4); p4 = fmaf(g[18], wv[4].z, p4); p4 = fmaf(g[19], wv[4].w, p4); \
    p5 = fmaf(g[21], wv[5].y, p5); p5 = fmaf(g[22], wv[5].z, p5); p5 = fmaf(g[23], wv[5].w, p5); \
    p6 = fmaf(g[25], wv[6].y, p6); p6 = fmaf(g[26], wv[6].z, p6); p6 = fmaf(g[27], wv[6].w, p6); \
    p7 = fmaf(g[29], wv[7].y, p7); p7 = fmaf(g[30], wv[7].z, p7); p7 = fmaf(g[31], wv[7].w, p7); \
    z = ((p0 + p1) + (p2 + p3)) + ((p4 + p5) + (p6 + p7));

#define S_ALL                                                                          \
    S_STEP(0, hv[0].x) S_STEP(1, hv[0].y) S_STEP(2, hv[0].z) S_STEP(3, hv[0].w)        \
    S_STEP(4, hv[1].x) S_STEP(5, hv[1].y) S_STEP(6, hv[1].z) S_STEP(7, hv[1].w)

    // ---- main loop: groups 0..126 ----
#pragma unroll 1
    for (int G = 0; G < NGRP - 1; ++G) {
        DOT8                                     // consumes gathers issued last group
        S_ALL                                    // within-group serial corrections
        const float t = tanh6(z);                // z final for every lane (hs==0 for s>=myj)
        act[(IN_SIZE + G * 8 + myj) * COLS + c] = t;     // 64 unique cells, no mask
        if (G >= NGRP - 2) {                     // group 126: output nodes 1008..1015
            const size_t o = (size_t)(G * 8 + myj - (N_NODES - OUT_SIZE)) * BATCH + c0 + c;
            if (isbf16) outb[o] = f2bf_rne(t); else outf[o] = t;
        }
        // gathers for group G+1 (AFTER write(G): stale rows = group G+1 only)
#pragma unroll
        for (int r4 = 0; r4 < 8; ++r4) {
            g[4 * r4 + 0] = act[idv[r4].x * COLS + c];
            g[4 * r4 + 1] = act[idv[r4].y * COLS + c];
            g[4 * r4 + 2] = act[idv[r4].z * COLS + c];
            g[4 * r4 + 3] = act[idv[r4].w * COLS + c];
        }
        // stream next: w(G+1), hs(G+1), ids(G+2 clamped)
        const int Gi = (G + 2 < NGRP) ? G + 2 : NGRP - 1;
#pragma unroll
        for (int r = 0; r < 8; ++r) wv[r] = pW[(G + 1) * 64 + r];
        hv[0] = pH4[(G + 1) * 16]; hv[1] = pH4[(G + 1) * 16 + 1];
#pragma unroll
        for (int r = 0; r < 8; ++r) idv[r] = pI[Gi * 64 + r];
    }
    // ---- peeled last group 127 (output nodes 1016..1023; no write/gather) ----
    {
        DOT8
        S_ALL
        const float t = tanh6(z);
        const size_t o = (size_t)(127 * 8 + myj - (N_NODES - OUT_SIZE)) * BATCH + c0 + c;
        if (isbf16) outb[o] = f2bf_rne(t); else outf[o] = t;
    }
#undef S_ALL
#undef DOT8
#undef S_STEP
}

extern "C" void kernel_launch(void* const* d_in, const int* in_sizes, int n_in,
                              void* d_out, int out_size, void* d_ws, size_t ws_size,
                              hipStream_t stream) {
    const void* x   = d_in[0];                   // [BATCH][IN_SIZE]
    const void* w   = d_in[1];                   // [N_NODES][DEG]
    const int* idxs = (const int*)d_in[2];       // [N_NODES][DEG]

    float* wf  = (float*)d_ws;                                          // 128 KB
    float* hst = (float*)((char*)d_ws + (size_t)N_NODES * DEG * 4);     // 32 KB
    int* flag  = (int*)((char*)d_ws + ((ws_size - 16) & ~(size_t)15));

    ne_detect<<<1, 64, 0, stream>>>(x, flag);
    ne_prep<<<32, 256, 0, stream>>>(w, idxs, wf, hst, flag);

    // 2048 single-wave blocks, 40 KB LDS -> 4 blocks/CU, 2 rounds, no barriers
    ne_forward<<<dim3(BATCH / COLS), dim3(64), 0, stream>>>(x, wf, idxs, hst, d_out, flag);
}

// Round 7
// 289.091 us; speedup vs baseline: 2.7212x; 2.7212x over previous
//
#include <hip/hip_runtime.h>

#define IN_SIZE 256
#define N_NODES 1024
#define DEG 32
#define BATCH 16384
#define OUT_SIZE 16
#define COLS 4                        // batch columns per single-wave block
#define N_ROWS (IN_SIZE + N_NODES)    // 1280 activation rows (fp32 in LDS)
#define NPAIR (N_NODES / 2)           // 512 node pairs

// RNE float -> bf16
__device__ __forceinline__ unsigned short f2bf_rne(float f) {
    const unsigned u = __float_as_uint(f);
    return (unsigned short)((u + 0x7FFFu + ((u >> 16) & 1u)) >> 16);
}

// overflow-free tanh: s = e^{-2|z|}, t = sign(z)*(1-s)/(1+s)
__device__ __forceinline__ float tanh6(float z) {
    const float s = __expf(-2.0f * fabsf(z));
    const float r = __builtin_amdgcn_rcpf(1.0f + s);
    return copysignf(fmaf(-s, r, r), z);
}

// butterfly add across lane bits {0,1,2}: quad_perm(B1)=xor1, quad_perm(4E)=xor2,
// row_half_mirror(0x141)=xor-to-7 within 8. Full 8-lane-group sum in every lane.
template <int CTRL>
__device__ __forceinline__ float dpp_add(float v) {
    return v + __int_as_float(__builtin_amdgcn_mov_dpp(__float_as_int(v), CTRL, 0xF, 0xF, true));
}
// cross-half exchange within a 16-lane row: row_ror:8 == lane^8 (HW-proven ctrl 0x128)
__device__ __forceinline__ float dpp_ror8(float v) {
    return __int_as_float(__builtin_amdgcn_mov_dpp(__float_as_int(v), 0x128, 0xF, 0xF, true));
}

// ---------------------------------------------------------------------------
// Runtime dtype detector (unchanged).
// ---------------------------------------------------------------------------
__global__ __launch_bounds__(64) void ne_detect(const void* __restrict__ xraw,
                                                int* __restrict__ flag) {
    const unsigned short* xb = (const unsigned short*)xraw;
    const int tid = threadIdx.x;
    int plausible = 0;
    for (int k = tid; k < 2048; k += 64) {
        const float v = __uint_as_float((unsigned)xb[2 * k] << 16);
        const float a = fabsf(v);
        plausible += (a == 0.0f) || (a > 1e-3f && a < 1e3f) ? 1 : 0;
    }
    for (int off = 32; off > 0; off >>= 1) plausible += __shfl_down(plausible, off);
    if (tid == 0) *flag = (plausible >= (2048 * 9) / 10) ? 1 : 0;
}

// ---------------------------------------------------------------------------
// Packed per-(node, fan-in-quad) tables, all hot-loop loads become
// table[(P<<4) + (lane&15)] (P = pair index):
//   pki[n*8+qq] = int4 ids[n][4qq..4qq+3]
//   pkw[n*8+qq] = float4 w  [n][4qq..4qq+3]   (fp32)
//   hzr[n*8+r]  = float4 hazard coeffs, replicated r=0..7 (vector load):
//     h_k(n) = sum_r w[n][r]*[idx[n][r]==256+n-k]  (only if n>=k)
//     even n: {ha,hb,hc} = {h1, h2, 0 }   (pre-folds: ha*t_{n-1} + hb*t_{n-2})
//     odd  n: {ha,hb,hc} = {h2, h3, h1}   (hc*t_{n-1} applied serially in-step)
// ---------------------------------------------------------------------------
__global__ __launch_bounds__(256) void ne_prep(const void* __restrict__ wraw,
                                               const int* __restrict__ idxs,
                                               int4* __restrict__ pki,
                                               float4* __restrict__ pkw,
                                               float4* __restrict__ hzr,
                                               const int* __restrict__ flag) {
    const int isbf16 = *flag;                    // uniform
    const int tid = blockIdx.x * 256 + threadIdx.x;
    const int stride = gridDim.x * 256;
    const unsigned short* wb = (const unsigned short*)wraw;
    const float* wsrc = (const float*)wraw;
    for (int k = tid; k < N_NODES * 8; k += stride) {   // k = n*8 + qq
        const int n = k >> 3, qq = k & 7;
        const int e = n * DEG + qq * 4;
        pki[k] = make_int4(idxs[e], idxs[e + 1], idxs[e + 2], idxs[e + 3]);
        float w0 = isbf16 ? __uint_as_float((unsigned)wb[e + 0] << 16) : wsrc[e + 0];
        float w1 = isbf16 ? __uint_as_float((unsigned)wb[e + 1] << 16) : wsrc[e + 1];
        float w2 = isbf16 ? __uint_as_float((unsigned)wb[e + 2] << 16) : wsrc[e + 2];
        float w3 = isbf16 ? __uint_as_float((unsigned)wb[e + 3] << 16) : wsrc[e + 3];
        pkw[k] = make_float4(w0, w1, w2, w3);
    }
    for (int n = tid; n < N_NODES; n += stride) {
        float h1 = 0.0f, h2 = 0.0f, h3 = 0.0f;
        const int r1 = IN_SIZE + n - 1, r2 = IN_SIZE + n - 2, r3 = IN_SIZE + n - 3;
        for (int r = 0; r < DEG; ++r) {
            const int id = idxs[n * DEG + r];
            const float w = isbf16 ? __uint_as_float((unsigned)wb[n * DEG + r] << 16)
                                   : wsrc[n * DEG + r];
            if (n >= 1 && id == r1) h1 += w;
            if (n >= 2 && id == r2) h2 += w;
            if (n >= 3 && id == r3) h3 += w;
        }
        const float4 hp = (n & 1) ? make_float4(h2, h3, h1, 0.0f)
                                  : make_float4(h1, h2, 0.0f, 0.0f);
#pragma unroll
        for (int r = 0; r < 8; ++r) hzr[n * 8 + r] = hp;
    }
}

// ---------------------------------------------------------------------------
// Node-PAIR steps, COLS=4 (20 KB LDS -> 8 single-wave blocks/CU, 2 waves/SIMD).
// lane = c*16 + h*8 + q: q = fan-in quad (4 elems), h = node parity in pair,
// c = batch column. Per pair P (nodes 2P, 2P+1):
//   DOT: 4 gathers+4 FMA/lane; ONE 3-DPP reduce serves both halves.
//   pre-folds: z += ha*t_{P-1,odd} + hb*t_{P-1,even}  (stale-row corrections)
//   serial: t1=tanh(z); ror8 -> odd half gets t_even; z+=hc*t_even; t=tanh(z)
//           (even half: hc=0 -> bitwise-identical recompute, deterministic)
//   write both rows (q==0 lanes); broadcast pair's t's via ror8 for next folds
//   issue gathers pair P+2 (stale rows = pairs P+1,P+2 -> pre-zeroed, covered
//   by ha/hb/hc); refill streams (pair P+2 data, ids P+4) - all dwordx4.
// Single wave => in-order DS => stale reads deterministically 0; no barriers.
// ---------------------------------------------------------------------------
__global__ __launch_bounds__(64) void ne_forward(const void* __restrict__ xraw,
                                                 const int4* __restrict__ pki,
                                                 const float4* __restrict__ pkw,
                                                 const float4* __restrict__ hzr,
                                                 void* __restrict__ outraw,
                                                 const int* __restrict__ flag) {
    __shared__ float act[N_ROWS * COLS];         // 20480 B -> 8 blocks/CU
    const int lane = threadIdx.x;
    const int q = lane & 7;                      // fan-in quad 0..7
    const int h = (lane >> 3) & 1;               // node parity in pair
    const int c = lane >> 4;                     // batch column 0..3
    const int l15 = lane & 15;                   // h*8+q: per-lane table offset
    const int c0 = blockIdx.x * COLS;
    const int isbf16 = *flag;                    // uniform
    float* outf = (float*)outraw;
    unsigned short* outb = (unsigned short*)outraw;

    // ---- zero node rows so stale gathers read exactly 0.0 ----
    {
        float4* az = (float4*)(act + IN_SIZE * COLS);   // 1024 float4
#pragma unroll
        for (int t = 0; t < 16; ++t) az[t * 64 + lane] = make_float4(0.f, 0.f, 0.f, 0.f);
    }
    // ---- seed input rows 0..255 from raw x: lane seeds rows l15*16..+15, col c ----
    {
        const int b = c;
        if (isbf16) {
            const unsigned short* xb =
                (const unsigned short*)xraw + (size_t)(c0 + b) * IN_SIZE + l15 * 16;
#pragma unroll
            for (int t = 0; t < 2; ++t) {
                const uint4 v = *(const uint4*)(xb + t * 8);
                const int k0 = l15 * 16 + t * 8;
                act[(k0 + 0) * COLS + b] = __uint_as_float(v.x << 16);
                act[(k0 + 1) * COLS + b] = __uint_as_float(v.x & 0xFFFF0000u);
                act[(k0 + 2) * COLS + b] = __uint_as_float(v.y << 16);
                act[(k0 + 3) * COLS + b] = __uint_as_float(v.y & 0xFFFF0000u);
                act[(k0 + 4) * COLS + b] = __uint_as_float(v.z << 16);
                act[(k0 + 5) * COLS + b] = __uint_as_float(v.z & 0xFFFF0000u);
                act[(k0 + 6) * COLS + b] = __uint_as_float(v.w << 16);
                act[(k0 + 7) * COLS + b] = __uint_as_float(v.w & 0xFFFF0000u);
            }
        } else {
            const float* xs = (const float*)xraw + (size_t)(c0 + b) * IN_SIZE + l15 * 16;
#pragma unroll
            for (int t = 0; t < 4; ++t) {
                const float4 v = *(const float4*)(xs + t * 4);
                const int k0 = l15 * 16 + t * 4;
                act[(k0 + 0) * COLS + b] = v.x;
                act[(k0 + 1) * COLS + b] = v.y;
                act[(k0 + 2) * COLS + b] = v.z;
                act[(k0 + 3) * COLS + b] = v.w;
            }
        }
    }
    // single wave: in-order DS pipeline -> gathers below see the seed; no barrier

    // ---- prologue: gathers pairs 0,1; streams hold pair 0,1 data + ids of 2,3 ----
    const int4 i0 = pki[0 * 16 + l15];
    const int4 i1 = pki[1 * 16 + l15];
    float gA0 = act[i0.x * COLS + c], gA1 = act[i0.y * COLS + c],
          gA2 = act[i0.z * COLS + c], gA3 = act[i0.w * COLS + c];
    float gB0 = act[i1.x * COLS + c], gB1 = act[i1.y * COLS + c],
          gB2 = act[i1.z * COLS + c], gB3 = act[i1.w * COLS + c];
    int4   idv0 = pki[2 * 16 + l15], idv1 = pki[3 * 16 + l15];
    float4 wv0 = pkw[0 * 16 + l15], wv1 = pkw[1 * 16 + l15];
    float4 hz0 = hzr[0 * 16 + l15], hz1 = hzr[1 * 16 + l15];
    float tpA = 0.0f, tpB = 0.0f;                // t of prev pair: even, odd
    const bool hodd = (h == 1);

#define PAIRSTEP(P, G0, G1, G2, G3, IDV, WV, HZ, OUT, CLAMP)                           \
    {                                                                                  \
        float z = G0 * WV.x; z = fmaf(G1, WV.y, z);                                    \
        z = fmaf(G2, WV.z, z); z = fmaf(G3, WV.w, z);                                  \
        z = dpp_add<0xB1>(z); z = dpp_add<0x4E>(z); z = dpp_add<0x141>(z);             \
        z = fmaf(HZ.x, tpB, z); z = fmaf(HZ.y, tpA, z);                                \
        const float t1 = tanh6(z);                                                     \
        const float to = dpp_ror8(t1);           /* odd half receives t_even */        \
        z = fmaf(HZ.z, to, z);                                                         \
        const float t = tanh6(z);                /* even half: identical recompute */  \
        if (q == 0) {                                                                  \
            act[(IN_SIZE + 2 * (P) + h) * COLS + c] = t;                               \
            if (OUT) {                                                                 \
                const size_t o =                                                       \
                    (size_t)(2 * (P) + h - (N_NODES - OUT_SIZE)) * BATCH + c0 + c;     \
                if (isbf16) outb[o] = f2bf_rne(t); else outf[o] = t;                   \
            }                                                                          \
        }                                                                              \
        const float o2 = dpp_ror8(t);            /* other half's final t */            \
        tpA = hodd ? o2 : t;                     /* t_even of this pair */             \
        tpB = hodd ? t : o2;                     /* t_odd  of this pair */             \
        /* issue gathers for pair P+2 (after write(P): stale = pairs P+1,P+2) */       \
        G0 = act[IDV.x * COLS + c]; G1 = act[IDV.y * COLS + c];                        \
        G2 = act[IDV.z * COLS + c]; G3 = act[IDV.w * COLS + c];                        \
        /* refill streams: ids pair P+4, w/hz pair P+2 (flight 2 pair-steps) */        \
        { const int Pn = (CLAMP) ? (((P) + 4 < NPAIR) ? (P) + 4 : NPAIR - 1) : (P) + 4;\
          const int Pw = (CLAMP) ? (((P) + 2 < NPAIR) ? (P) + 2 : NPAIR - 1) : (P) + 2;\
          IDV = pki[(Pn << 4) + l15];                                                  \
          WV  = pkw[(Pw << 4) + l15];                                                  \
          HZ  = hzr[(Pw << 4) + l15]; }                                                \
    }

    // main loop: pairs 0..503 (nodes 0..1007) — no output, no clamp (P+4 <= 507)
#pragma unroll 1
    for (int P = 0; P < NPAIR - 8; P += 2) {
        PAIRSTEP(P,     gA0, gA1, gA2, gA3, idv0, wv0, hz0, 0, 0)
        PAIRSTEP(P + 1, gB0, gB1, gB2, gB3, idv1, wv1, hz1, 0, 0)
    }
    // epilogue: pairs 504..511 (nodes 1008..1023 — all outputs)
    {
        const int P = NPAIR - 8;                 // 504
        PAIRSTEP(P + 0, gA0, gA1, gA2, gA3, idv0, wv0, hz0, 1, 1)
        PAIRSTEP(P + 1, gB0, gB1, gB2, gB3, idv1, wv1, hz1, 1, 1)
        PAIRSTEP(P + 2, gA0, gA1, gA2, gA3, idv0, wv0, hz0, 1, 1)
        PAIRSTEP(P + 3, gB0, gB1, gB2, gB3, idv1, wv1, hz1, 1, 1)
        PAIRSTEP(P + 4, gA0, gA1, gA2, gA3, idv0, wv0, hz0, 1, 1)
        PAIRSTEP(P + 5, gB0, gB1, gB2, gB3, idv1, wv1, hz1, 1, 1)
        PAIRSTEP(P + 6, gA0, gA1, gA2, gA3, idv0, wv0, hz0, 1, 1)
        PAIRSTEP(P + 7, gB0, gB1, gB2, gB3, idv1, wv1, hz1, 1, 1)
    }
#undef PAIRSTEP
}

extern "C" void kernel_launch(void* const* d_in, const int* in_sizes, int n_in,
                              void* d_out, int out_size, void* d_ws, size_t ws_size,
                              hipStream_t stream) {
    const void* x   = d_in[0];                   // [BATCH][IN_SIZE]
    const void* w   = d_in[1];                   // [N_NODES][DEG]
    const int* idxs = (const int*)d_in[2];       // [N_NODES][DEG]

    int4*   pki = (int4*)d_ws;                                           // 256 KB
    float4* pkw = (float4*)((char*)d_ws + (size_t)256 * 1024);           // 256 KB
    float4* hzr = (float4*)((char*)d_ws + (size_t)512 * 1024);           // 128 KB
    int* flag   = (int*)((char*)d_ws + ((ws_size - 16) & ~(size_t)15));

    ne_detect<<<1, 64, 0, stream>>>(x, flag);
    ne_prep<<<32, 256, 0, stream>>>(w, idxs, pki, pkw, hzr, flag);

    // 4096 single-wave blocks, 20 KB LDS -> 8 blocks/CU (2 waves/SIMD),
    // 2 scheduling rounds, zero barriers.
    ne_forward<<<dim3(BATCH / COLS), dim3(64), 0, stream>>>(x, pki, pkw, hzr, d_out, flag);
}